// Round 15
// baseline (146.390 us; speedup 1.0000x reference)
//
#include <hip/hip_runtime.h>

#define GRID_D 64
#define NN (GRID_D * GRID_D)   // 4096 nodes per image
#define H 64
#define C_IN 12
#define B_SZ 128
#define LN_EPS 1e-5f

typedef _Float16 f16x8 __attribute__((ext_vector_type(8)));
typedef _Float16 f16x4 __attribute__((ext_vector_type(4)));
typedef float    f32x4 __attribute__((ext_vector_type(4)));

#define AS1 __attribute__((address_space(1)))
#define AS3 __attribute__((address_space(3)))

// ---------------------------------------------------------------------------
// Kernel 0: weight prep — plain-transposed f16 copies of Ws/Wn.
// wt[l][g][j][k] = W[l,g][k][j]
// ---------------------------------------------------------------------------
__global__ __launch_bounds__(256) void k_prep(
    const float* __restrict__ ws_, const float* __restrict__ wn_,
    _Float16* __restrict__ wt)
{
    int i = blockIdx.x * 256 + threadIdx.x;      // 0..24575
    if (i < 3 * 2 * 4096) {
        int l = i >> 13, g = (i >> 12) & 1, j = (i >> 6) & 63, k = i & 63;
        const float* W = (g ? wn_ : ws_) + l * 4096;
        wt[i] = (_Float16)W[k * 64 + j];
    }
}

// ---------------------------------------------------------------------------
// Kernel 1: input projection  h0[b,n,j] = sum_c x[b,c,n] * w_in[c,j] + b_in[j]
// ---------------------------------------------------------------------------
__global__ __launch_bounds__(256) void k_inproj(
    const float* __restrict__ x, const float* __restrict__ w_in,
    const float* __restrict__ b_in, _Float16* __restrict__ h)
{
    int bid = blockIdx.x;            // b*64 + r
    int b = bid >> 6, r = bid & 63;
    __shared__ float xs[C_IN][GRID_D];
    __shared__ float ws[C_IN][H];
    int tid = threadIdx.x;
    const float* xb = x + (size_t)b * C_IN * NN + (size_t)r * GRID_D;
    for (int idx = tid; idx < C_IN * GRID_D; idx += 256) {
        int c = idx >> 6, n = idx & 63;
        xs[c][n] = xb[(size_t)c * NN + n];
        ws[c][n] = w_in[idx];
    }
    __syncthreads();
    int n = tid >> 2;                // node 0..63
    int j0 = (tid & 3) * 16;         // 16-feat group
    float acc[16];
    #pragma unroll
    for (int t = 0; t < 16; ++t) acc[t] = b_in[j0 + t];
    #pragma unroll
    for (int c = 0; c < C_IN; ++c) {
        float xv = xs[c][n];
        #pragma unroll
        for (int t = 0; t < 16; ++t) acc[t] += xv * ws[c][j0 + t];
    }
    _Float16* hp = h + (size_t)(b * NN + r * GRID_D + n) * H + j0;
    f16x8 o0, o1;
    #pragma unroll
    for (int t = 0; t < 8; ++t) { o0[t] = (_Float16)acc[t]; o1[t] = (_Float16)acc[8 + t]; }
    *(f16x8*)hp = o0;
    *(f16x8*)(hp + 8) = o1;
}

// ---------------------------------------------------------------------------
// Kernel 2: FUSED 3 layers + head; wavefront pipeline with DEDICATED STAGERS.
// Block = 1024 thr (16 waves) owns 32 output rows of one image; grid = 256
// = 1 block/CU, zero tail. Waves 0-3: stagers — issue global_load_lds for
// h0 row p into ring0 and absorb the vmcnt drain at the barrier themselves
// (overlapped with compute). Waves 4-7/8-11/12-15: layer 1/2/3+head, all
// reading rings only (NO global loads -> no drain on the compute path).
// Step s (0..40): stage p=r0-3+s; grp g computes q=p-2-2g. Mod-4 ring slots
// (writer q&3 disjoint from readers (q-3..q-1)&3). Weights: 16 f16x8/lane
// in VGPRs, pinned (launch_bounds min=3 — the only setting that does not
// demote the pin; min=4 demoted twice). setprio(1) around MFMA (T5: pays
// when waves are role-split).
// ---------------------------------------------------------------------------
__global__ __launch_bounds__(1024, 3) void k_fused(
    const _Float16* __restrict__ h0, float* __restrict__ logits,
    const _Float16* __restrict__ wtb,      // [3][2][64][64] transposed f16
    const float* __restrict__ cb, const float* __restrict__ lg,
    const float* __restrict__ lb,
    const float* __restrict__ w_head, const float* __restrict__ b_head)
{
    __shared__ _Float16 ring[3][4][4096];  // 96 KB (h1, h2, h3-input rings)
    __shared__ float    pl[640];           // cb|lg|lb per layer + w_head

    int tid = threadIdx.x, ln = tid & 63, wv = tid >> 6;
    int bid = blockIdx.x;
    int img = bid >> 1, chunk = bid & 1;
    int r0 = chunk << 5;                   // 32 owned output rows
    const _Float16* hg = h0 + ((size_t)img << 18);

    bool stager = (wv < 4);
    int grp = stager ? 0 : (wv >> 2) - 1;  // compute waves: 0,1,2
    int ct  = wv & 3;                      // col tile (compute waves)
    int lrow = ln & 15, kgrp = ln >> 4, kq = kgrp * 4;
    int col = ct * 16 + lrow;
    int cs = lrow & 7;
    bool cl = (col > 0), cr = (col < 63);

    // ---- weights (compute waves only): 16 frags = 64 VGPR, pinned ----
    f16x8 wsf[2][4], wnf[2][4];
    if (!stager) {
        const _Float16* wg = wtb + grp * 8192;
        #pragma unroll
        for (int ks = 0; ks < 2; ++ks) {
            int k0 = ks * 32 + kq * 2;
            #pragma unroll
            for (int ft = 0; ft < 4; ++ft) {
                int j = ft * 16 + lrow;
                wsf[ks][ft] = *(const f16x8*)(wg + (j << 6) + k0);
                wnf[ks][ft] = *(const f16x8*)(wg + ((64 + j) << 6) + k0);
            }
        }
        #pragma unroll
        for (int ks = 0; ks < 2; ++ks)
            #pragma unroll
            for (int ft = 0; ft < 4; ++ft)
                asm volatile("" : "+v"(wsf[ks][ft]), "+v"(wnf[ks][ft]));
    }

    // ---- params to LDS ----
    if (tid < 576) {
        int l = tid / 192, r = tid % 192;
        pl[tid] = (r < 64) ? cb[l * 64 + r]
                : (r < 128) ? lg[l * 64 + r - 64] : lb[l * 64 + r - 128];
    } else if (tid < 640) {
        pl[tid] = w_head[tid - 576];
    }
    __syncthreads();

    const float* myp = pl + grp * 192;
    float bh = b_head[0];

    // stage range (h0 rows) and per-group compute ranges, clipped to image
    int lo0 = (r0 - 3 < 0) ? 0 : r0 - 3;
    int hi0 = (r0 + 34 > 63) ? 63 : r0 + 34;
    int loC, hiC;
    if (grp == 0)      { loC = (r0 - 2 < 0) ? 0 : r0 - 2; hiC = (r0 + 33 > 63) ? 63 : r0 + 33; }
    else if (grp == 1) { loC = (r0 - 1 < 0) ? 0 : r0 - 1; hiC = (r0 + 32 > 63) ? 63 : r0 + 32; }
    else               { loC = r0;                         hiC = r0 + 31; }

    const _Float16* rin = &ring[grp][0][0];
    _Float16* rout      = (grp < 2) ? &ring[grp + 1][0][0] : nullptr;

    // pre-swizzled per-lane pieces for staging (rule 21)
    int snode = ln >> 3;                       // node within 8-node chunk
    int sslot = ((ln & 7) ^ snode) << 3;       // swizzled 16B slot (elems)

    #pragma unroll 1
    for (int s = 0; s <= 40; ++s) {
        int p = r0 - 3 + s;
        if (stager) {
            if (p >= lo0 && p <= hi0) {
                _Float16* slot = &ring[0][p & 3][0];
                #pragma unroll
                for (int i = 0; i < 2; ++i) {
                    int c = wv * 2 + i;                    // 8-node chunk 0..7
                    const _Float16* src = hg
                        + (((size_t)(p * GRID_D + c * 8 + snode)) << 6) + sslot;
                    __builtin_amdgcn_global_load_lds(
                        (const AS1 void*)src, (AS3 void*)(slot + c * 512), 16, 0, 0);
                }
            }
        } else {
            int q = p - 2 - 2 * grp;               // my group's row this step
            if (q >= loC && q <= hiC) {
                _Float16 hinv = (_Float16)(1.0f / (float)((q > 0) + (q < 63) + cl + cr));
                f16x8 z = {};
                const _Float16* rc = rin + ((q & 3) << 12);
                const _Float16* ru = rin + (((q - 1) & 3) << 12);
                const _Float16* rd = rin + (((q + 1) & 3) << 12);

                f32x4 acc[4];
                #pragma unroll
                for (int ft = 0; ft < 4; ++ft) acc[ft] = (f32x4){0.f, 0.f, 0.f, 0.f};

                // phase 1: Ws^T @ self^T
                __builtin_amdgcn_s_setprio(1);
                #pragma unroll
                for (int ks = 0; ks < 2; ++ks) {
                    int sl = ((ks * 4 + kgrp) ^ cs) << 3;
                    f16x8 a = *(const f16x8*)(rc + (col << 6) + sl);
                    #pragma unroll
                    for (int ft = 0; ft < 4; ++ft)
                        acc[ft] = __builtin_amdgcn_mfma_f32_16x16x32_f16(wsf[ks][ft], a, acc[ft], 0, 0, 0);
                }
                // phase 2: Wn^T @ agg^T
                #pragma unroll
                for (int ks = 0; ks < 2; ++ks) {
                    int c8 = ks * 4 + kgrp;
                    int sl = (c8 ^ cs) << 3;
                    f16x8 u = (q > 0)  ? *(const f16x8*)(ru + (col << 6) + sl) : z;
                    f16x8 d = (q < 63) ? *(const f16x8*)(rd + (col << 6) + sl) : z;
                    int cm = col - cl;
                    f16x8 lv = *(const f16x8*)(rc + (cm << 6) + ((c8 ^ (cm & 7)) << 3));
                    if (!cl) lv = z;
                    int cp = col + cr;
                    f16x8 rv = *(const f16x8*)(rc + (cp << 6) + ((c8 ^ (cp & 7)) << 3));
                    if (!cr) rv = z;
                    f16x8 sm = (lv + rv) + (u + d);
                    f16x8 g;
                    #pragma unroll
                    for (int e = 0; e < 8; ++e) g[e] = sm[e] * hinv;
                    #pragma unroll
                    for (int ft = 0; ft < 4; ++ft)
                        acc[ft] = __builtin_amdgcn_mfma_f32_16x16x32_f16(wnf[ks][ft], g, acc[ft], 0, 0, 0);
                }
                __builtin_amdgcn_s_setprio(0);

                // epilogue: +bias, LN, residual+ReLU -> ring or logits
                float s1 = 0.f, s2 = 0.f;
                #pragma unroll
                for (int ft = 0; ft < 4; ++ft) {
                    f32x4 qv = *(const f32x4*)&myp[ft * 16 + kq];
                    acc[ft] += qv;
                    #pragma unroll
                    for (int t = 0; t < 4; ++t) { float xv = acc[ft][t]; s1 += xv; s2 += xv * xv; }
                }
                s1 += __shfl_xor(s1, 16); s1 += __shfl_xor(s1, 32);
                s2 += __shfl_xor(s2, 16); s2 += __shfl_xor(s2, 32);
                float mu   = s1 * (1.0f / H);
                float var  = s2 * (1.0f / H) - mu * mu;
                float rstd = rsqrtf(var + LN_EPS);

                if (grp < 2) {
                    _Float16* outp = rout + ((q & 3) << 12) + (col << 6);
                    #pragma unroll
                    for (int ft = 0; ft < 4; ++ft) {
                        f32x4 lgq = *(const f32x4*)&myp[64 + ft * 16 + kq];
                        f32x4 lbq = *(const f32x4*)&myp[128 + ft * 16 + kq];
                        int slot = (ft * 2 + (kgrp >> 1)) ^ cs;
                        f16x4 rq = *(const f16x4*)(rc + (col << 6) + (slot << 3) + (kgrp & 1) * 4);
                        f16x4 oq;
                        #pragma unroll
                        for (int t = 0; t < 4; ++t) {
                            float o = (float)rq[t]
                                    + fmaxf((acc[ft][t] - mu) * rstd * lgq[t] + lbq[t], 0.f);
                            oq[t] = (_Float16)o;
                        }
                        *(f16x4*)(outp + (slot << 3) + (kgrp & 1) * 4) = oq;
                    }
                } else {
                    float part = 0.f;
                    #pragma unroll
                    for (int ft = 0; ft < 4; ++ft) {
                        f32x4 lgq = *(const f32x4*)&myp[64 + ft * 16 + kq];
                        f32x4 lbq = *(const f32x4*)&myp[128 + ft * 16 + kq];
                        f32x4 whq = *(const f32x4*)&pl[576 + ft * 16 + kq];
                        int slot = (ft * 2 + (kgrp >> 1)) ^ cs;
                        f16x4 rq = *(const f16x4*)(rc + (col << 6) + (slot << 3) + (kgrp & 1) * 4);
                        #pragma unroll
                        for (int t = 0; t < 4; ++t) {
                            float o = (float)rq[t]
                                    + fmaxf((acc[ft][t] - mu) * rstd * lgq[t] + lbq[t], 0.f);
                            part += o * whq[t];
                        }
                    }
                    part += __shfl_xor(part, 16);
                    part += __shfl_xor(part, 32);
                    if (kgrp == 0)
                        logits[(size_t)img * NN + q * GRID_D + col] = part + bh;
                }
            }
        }
        __syncthreads();   // stagers drain their own vmcnt; compute waves don't
    }
}

// ---------------------------------------------------------------------------
extern "C" void kernel_launch(void* const* d_in, const int* in_sizes, int n_in,
                              void* d_out, int out_size, void* d_ws, size_t ws_size,
                              hipStream_t stream) {
    const float* x      = (const float*)d_in[0];
    // d_in[1] edge_index: fixed grid 4-neighborhood -> computed as stencil, unused
    const float* w_in   = (const float*)d_in[2];
    const float* b_in   = (const float*)d_in[3];
    const float* w_self = (const float*)d_in[4];
    const float* w_neigh= (const float*)d_in[5];
    const float* conv_b = (const float*)d_in[6];
    const float* ln_g   = (const float*)d_in[7];
    const float* ln_b   = (const float*)d_in[8];
    const float* w_head = (const float*)d_in[9];
    const float* b_head = (const float*)d_in[10];
    float* out = (float*)d_out;

    char* base = (char*)d_ws;
    const size_t HBYTES = (size_t)B_SZ * NN * H * sizeof(_Float16);   // 64 MiB
    _Float16* h_a = (_Float16*)base;
    _Float16* wtb = (_Float16*)(base + HBYTES);                       // 48 KiB

    k_prep<<<96, 256, 0, stream>>>(w_self, w_neigh, wtb);
    k_inproj<<<B_SZ * GRID_D, 256, 0, stream>>>(x, w_in, b_in, h_a);
    k_fused<<<B_SZ * 2, 1024, 0, stream>>>(
        h_a, out, wtb, conv_b, ln_g, ln_b, w_head, b_head);
}

// Round 16
// 107.543 us; speedup vs baseline: 1.3612x; 1.3612x over previous
//
#include <hip/hip_runtime.h>

#define GRID_D 64
#define NN (GRID_D * GRID_D)   // 4096 nodes per image
#define H 64
#define C_IN 12
#define B_SZ 128
#define LN_EPS 1e-5f

typedef _Float16 f16x8 __attribute__((ext_vector_type(8)));
typedef _Float16 f16x4 __attribute__((ext_vector_type(4)));
typedef float    f32x4 __attribute__((ext_vector_type(4)));

#define AS1 __attribute__((address_space(1)))
#define AS3 __attribute__((address_space(3)))

// ---------------------------------------------------------------------------
// Kernel 1: input projection  h0[b,n,j] = sum_c x[b,c,n]*w_in[c,j] + b_in[j]
// Blocks 0..95 additionally transpose Ws/Wn to f16 (folded k_prep — saves a
// serial launch; wtb is consumed only by k_fused, launched after).
// ---------------------------------------------------------------------------
__global__ __launch_bounds__(256) void k_inproj(
    const float* __restrict__ x, const float* __restrict__ w_in,
    const float* __restrict__ b_in, _Float16* __restrict__ h,
    const float* __restrict__ ws_, const float* __restrict__ wn_,
    _Float16* __restrict__ wt)
{
    int bid = blockIdx.x;            // b*64 + r
    int b = bid >> 6, r = bid & 63;
    int tid = threadIdx.x;

    // folded weight prep: wt[l][g][j][k] = W[l,g][k][j]
    int pi = bid * 256 + tid;
    if (pi < 3 * 2 * 4096) {
        int l = pi >> 13, g = (pi >> 12) & 1, j = (pi >> 6) & 63, k = pi & 63;
        const float* W = (g ? wn_ : ws_) + l * 4096;
        wt[pi] = (_Float16)W[k * 64 + j];
    }

    __shared__ float xs[C_IN][GRID_D];
    __shared__ float ws[C_IN][H];
    const float* xb = x + (size_t)b * C_IN * NN + (size_t)r * GRID_D;
    for (int idx = tid; idx < C_IN * GRID_D; idx += 256) {
        int c = idx >> 6, n = idx & 63;
        xs[c][n] = xb[(size_t)c * NN + n];
        ws[c][n] = w_in[idx];
    }
    __syncthreads();
    int n = tid >> 2;                // node 0..63
    int j0 = (tid & 3) * 16;         // 16-feat group
    float acc[16];
    #pragma unroll
    for (int t = 0; t < 16; ++t) acc[t] = b_in[j0 + t];
    #pragma unroll
    for (int c = 0; c < C_IN; ++c) {
        float xv = xs[c][n];
        #pragma unroll
        for (int t = 0; t < 16; ++t) acc[t] += xv * ws[c][j0 + t];
    }
    _Float16* hp = h + (size_t)(b * NN + r * GRID_D + n) * H + j0;
    f16x8 o0, o1;
    #pragma unroll
    for (int t = 0; t < 8; ++t) { o0[t] = (_Float16)acc[t]; o1[t] = (_Float16)acc[8 + t]; }
    *(f16x8*)hp = o0;
    *(f16x8*)(hp + 8) = o1;
}

// stage one grid row (64 nodes x 64 f16 = 8KB) into ring0 slot; linear dest,
// pre-swizzled per-lane global source (rule 21). Waves 0..7, one gload each.
__device__ __forceinline__ void stage_row(
    const _Float16* hb, int grow, _Float16* slot, int wv, int ln)
{
    const _Float16* src = hb
        + (((size_t)(grow * GRID_D + wv * 8 + (ln >> 3))) << 6)
        + (((ln & 7) ^ (ln >> 3)) << 3);
    _Float16* dst = slot + wv * 512;
    __builtin_amdgcn_global_load_lds((const AS1 void*)src, (AS3 void*)dst, 16, 0, 0);
}

// ---------------------------------------------------------------------------
// Kernel 2: FUSED 3 layers + head. Persistent wavefront pipeline (= R10, the
// measured best: 98us, VGPR 80 with pins held). Block = 768 thr (12 waves)
// owns 32 output rows of one image (grid 256 = 1 block/CU). Step s: stage
// h0[p0] async into ring0 (waves 0-7); waves 0-3: h1[p0-2] (ring0->ring1);
// waves 4-7: h2[p0-4] (ring1->ring2); waves 8-11: h3[p0-6]+head -> logits.
// One barrier/step; mod-4 ring slots (writer q&3 disjoint from readers
// (q-3..q-1)&3). Weights: 16 f16x8/lane in VGPRs, pinned — ONLY stable at
// block=768 + min-waves=3 (cap 170); min>=4 or 1024-thr blocks demote
// (R11/R12/R15: VGPR 40/64/64). NEW vs R10: s_setprio around MFMA (T5 —
// wave role-split schedule is the regime where it pays, m191).
// ---------------------------------------------------------------------------
__global__ __launch_bounds__(768, 3) void k_fused(
    const _Float16* __restrict__ h0, float* __restrict__ logits,
    const _Float16* __restrict__ wtb,      // [3][2][64][64] transposed f16
    const float* __restrict__ cb, const float* __restrict__ lg,
    const float* __restrict__ lb,
    const float* __restrict__ w_head, const float* __restrict__ b_head)
{
    __shared__ _Float16 ring[3][4][4096];  // 96 KB
    __shared__ float    pl[640];           // cb|lg|lb per layer (3x192) + wh(64)

    int tid = threadIdx.x, ln = tid & 63, wv = tid >> 6;
    int bid = blockIdx.x;
    int img = bid >> 1, chunk = bid & 1;
    int r0 = chunk << 5;                   // 32 output rows
    const _Float16* hb = h0 + ((size_t)img << 18);

    int grp = wv >> 2;                     // 0,1,2 = layer-1,2,3
    int ct  = wv & 3;                      // col tile
    int lrow = ln & 15, kgrp = ln >> 4;
    int col = ct * 16 + lrow;
    int cs = col & 7;                      // == lrow & 7
    int kq = kgrp * 4;
    bool cl = (col > 0), cr = (col < 63);

    // ---- weights for my group's layer: 16 frags = 64 VGPR, pinned ----
    const _Float16* wg = wtb + grp * 8192;
    f16x8 wsf[2][4], wnf[2][4];
    #pragma unroll
    for (int ks = 0; ks < 2; ++ks) {
        int k0 = ks * 32 + kq * 2;         // ks*32 + kgrp*8
        #pragma unroll
        for (int ft = 0; ft < 4; ++ft) {
            int j = ft * 16 + lrow;
            wsf[ks][ft] = *(const f16x8*)(wg + (j << 6) + k0);
            wnf[ks][ft] = *(const f16x8*)(wg + ((64 + j) << 6) + k0);
        }
    }
    #pragma unroll
    for (int ks = 0; ks < 2; ++ks)
        #pragma unroll
        for (int ft = 0; ft < 4; ++ft)
            asm volatile("" : "+v"(wsf[ks][ft]), "+v"(wnf[ks][ft]));

    // ---- params to LDS ----
    if (tid < 576) {
        int l = tid / 192, r = tid % 192;
        pl[tid] = (r < 64) ? cb[l * 64 + r]
                : (r < 128) ? lg[l * 64 + r - 64] : lb[l * 64 + r - 128];
    } else if (tid < 640) {
        pl[tid] = w_head[tid - 576];
    }

    const float* myp = pl + grp * 192;
    float bh = b_head[0];

    // stage/compute validity ranges (clipped to image)
    int lo0 = (r0 - 3 < 0) ? 0 : r0 - 3, hi0 = (r0 + 34 > 63) ? 63 : r0 + 34;
    int loC, hiC;
    if (grp == 0)      { loC = (r0 - 2 < 0) ? 0 : r0 - 2; hiC = (r0 + 33 > 63) ? 63 : r0 + 33; }
    else if (grp == 1) { loC = (r0 - 1 < 0) ? 0 : r0 - 1; hiC = (r0 + 32 > 63) ? 63 : r0 + 32; }
    else               { loC = r0;                         hiC = r0 + 31; }

    _Float16* rin  = &ring[grp][0][0];                 // group g reads ring[g]
    _Float16* rout = (grp < 2) ? &ring[grp + 1][0][0] : nullptr;

    #pragma unroll 1
    for (int s = 0; s <= 40; ++s) {
        int p0 = r0 - 3 + s;
        if (wv < 8 && p0 >= lo0 && p0 <= hi0)
            stage_row(hb, p0, &ring[0][p0 & 3][0], wv, ln);

        int pr = p0 - 2 * grp - 2;                     // my group's row this step
        if (pr >= loC && pr <= hiC) {
            const _Float16* rc = rin + ((pr & 3) << 12);
            const _Float16* ru = rin + (((pr - 1) & 3) << 12);
            const _Float16* rd = rin + (((pr + 1) & 3) << 12);
            _Float16 hinv = (_Float16)(1.0f / (float)((pr > 0) + (pr < 63) + cl + cr));

            f32x4 acc[4];
            #pragma unroll
            for (int ft = 0; ft < 4; ++ft) acc[ft] = (f32x4){0.f, 0.f, 0.f, 0.f};

            // phase 1: Ws^T @ self^T
            __builtin_amdgcn_s_setprio(1);
            #pragma unroll
            for (int ks = 0; ks < 2; ++ks) {
                int sl = ((ks * 4 + kgrp) ^ cs) << 3;
                f16x8 a = *(const f16x8*)(rc + (col << 6) + sl);
                #pragma unroll
                for (int ft = 0; ft < 4; ++ft)
                    acc[ft] = __builtin_amdgcn_mfma_f32_16x16x32_f16(wsf[ks][ft], a, acc[ft], 0, 0, 0);
            }

            // phase 2: Wn^T @ agg^T
            #pragma unroll
            for (int ks = 0; ks < 2; ++ks) {
                int c8 = ks * 4 + kgrp;
                int sl = (c8 ^ cs) << 3;
                f16x8 z = {};
                f16x8 u = (pr > 0)  ? *(const f16x8*)(ru + (col << 6) + sl) : z;
                f16x8 d = (pr < 63) ? *(const f16x8*)(rd + (col << 6) + sl) : z;
                int cm = col - cl;
                f16x8 lv = *(const f16x8*)(rc + (cm << 6) + ((c8 ^ (cm & 7)) << 3));
                if (!cl) lv = z;
                int cp = col + cr;
                f16x8 rv = *(const f16x8*)(rc + (cp << 6) + ((c8 ^ (cp & 7)) << 3));
                if (!cr) rv = z;
                f16x8 sm = (lv + rv) + (u + d);
                f16x8 g;
                #pragma unroll
                for (int e = 0; e < 8; ++e) g[e] = sm[e] * hinv;
                #pragma unroll
                for (int ft = 0; ft < 4; ++ft)
                    acc[ft] = __builtin_amdgcn_mfma_f32_16x16x32_f16(wnf[ks][ft], g, acc[ft], 0, 0, 0);
            }
            __builtin_amdgcn_s_setprio(0);

            // epilogue: +bias, LN, residual+ReLU -> ring or logits
            float s1 = 0.f, s2 = 0.f;
            #pragma unroll
            for (int ft = 0; ft < 4; ++ft) {
                f32x4 q = *(const f32x4*)&myp[ft * 16 + kq];
                acc[ft] += q;
                #pragma unroll
                for (int t = 0; t < 4; ++t) { float xv = acc[ft][t]; s1 += xv; s2 += xv * xv; }
            }
            s1 += __shfl_xor(s1, 16); s1 += __shfl_xor(s1, 32);
            s2 += __shfl_xor(s2, 16); s2 += __shfl_xor(s2, 32);
            float mu   = s1 * (1.0f / H);
            float var  = s2 * (1.0f / H) - mu * mu;
            float rstd = rsqrtf(var + LN_EPS);

            const _Float16* res = rc + (col << 6);
            if (grp < 2) {
                _Float16* outp = rout + ((pr & 3) << 12) + (col << 6);
                #pragma unroll
                for (int ft = 0; ft < 4; ++ft) {
                    f32x4 lgq = *(const f32x4*)&myp[64 + ft * 16 + kq];
                    f32x4 lbq = *(const f32x4*)&myp[128 + ft * 16 + kq];
                    int slot = (ft * 2 + (kgrp >> 1)) ^ cs;
                    f16x4 rq = *(const f16x4*)(res + (slot << 3) + (kgrp & 1) * 4);
                    f16x4 oq;
                    #pragma unroll
                    for (int t = 0; t < 4; ++t) {
                        float o = (float)rq[t]
                                + fmaxf((acc[ft][t] - mu) * rstd * lgq[t] + lbq[t], 0.f);
                        oq[t] = (_Float16)o;
                    }
                    *(f16x4*)(outp + (slot << 3) + (kgrp & 1) * 4) = oq;
                }
            } else {
                float part = 0.f;
                #pragma unroll
                for (int ft = 0; ft < 4; ++ft) {
                    f32x4 lgq = *(const f32x4*)&myp[64 + ft * 16 + kq];
                    f32x4 lbq = *(const f32x4*)&myp[128 + ft * 16 + kq];
                    f32x4 whq = *(const f32x4*)&pl[576 + ft * 16 + kq];
                    int slot = (ft * 2 + (kgrp >> 1)) ^ cs;
                    f16x4 rq = *(const f16x4*)(res + (slot << 3) + (kgrp & 1) * 4);
                    #pragma unroll
                    for (int t = 0; t < 4; ++t) {
                        float o = (float)rq[t]
                                + fmaxf((acc[ft][t] - mu) * rstd * lgq[t] + lbq[t], 0.f);
                        part += o * whq[t];
                    }
                }
                part += __shfl_xor(part, 16);
                part += __shfl_xor(part, 32);
                if (kgrp == 0)
                    logits[(size_t)img * NN + pr * GRID_D + col] = part + bh;
            }
        }
        __syncthreads();   // lands stage (vmcnt drain) + publishes ring writes
    }
}

// ---------------------------------------------------------------------------
extern "C" void kernel_launch(void* const* d_in, const int* in_sizes, int n_in,
                              void* d_out, int out_size, void* d_ws, size_t ws_size,
                              hipStream_t stream) {
    const float* x      = (const float*)d_in[0];
    // d_in[1] edge_index: fixed grid 4-neighborhood -> computed as stencil, unused
    const float* w_in   = (const float*)d_in[2];
    const float* b_in   = (const float*)d_in[3];
    const float* w_self = (const float*)d_in[4];
    const float* w_neigh= (const float*)d_in[5];
    const float* conv_b = (const float*)d_in[6];
    const float* ln_g   = (const float*)d_in[7];
    const float* ln_b   = (const float*)d_in[8];
    const float* w_head = (const float*)d_in[9];
    const float* b_head = (const float*)d_in[10];
    float* out = (float*)d_out;

    char* base = (char*)d_ws;
    const size_t HBYTES = (size_t)B_SZ * NN * H * sizeof(_Float16);   // 64 MiB
    _Float16* h_a = (_Float16*)base;
    _Float16* wtb = (_Float16*)(base + HBYTES);                       // 48 KiB

    k_inproj<<<B_SZ * GRID_D, 256, 0, stream>>>(
        x, w_in, b_in, h_a, w_self, w_neigh, wtb);
    k_fused<<<B_SZ * 2, 768, 0, stream>>>(
        h_a, out, wtb, conv_b, ln_g, ln_b, w_head, b_head);
}